// Round 6
// baseline (16582.005 us; speedup 1.0000x reference)
//
#include <hip/hip_runtime.h>

#define Tn 512
#define In 40
#define Hn 256
#define Kn 4
#define On 16
#define RRES 4              // resident rec j2-chunks (j < 32)
#define NJ2 32              // total rec j2-chunks

typedef _Float16 half8  __attribute__((ext_vector_type(8)));
typedef _Float16 half2v __attribute__((ext_vector_type(2)));

template<int P>
static __device__ __forceinline__ half2v h2c(half8 v) {
    return __builtin_shufflevector(v, v, 2 * P, 2 * P + 1);
}
static __device__ __forceinline__ half8 ld8(const _Float16* p) {
    return *(const half8*)p;
}
static __device__ __forceinline__ float tanh_fast(float x) {
    float e = __expf(2.f * x);
    return 1.f - 2.f * __builtin_amdgcn_rcpf(e + 1.f);
}

// keep a loaded value alive in VGPRs (not rematerializable afterwards)
#define PIN(v) asm volatile("" : "+v"(v))

// acc += dot(hv, wv) over 8 fp16, via 4 fdot2 (compile-time extracts)
#define D8(acc, hv, wv) do { \
    acc = __builtin_amdgcn_fdot2(h2c<0>(hv), h2c<0>(wv), acc, false); \
    acc = __builtin_amdgcn_fdot2(h2c<1>(hv), h2c<1>(wv), acc, false); \
    acc = __builtin_amdgcn_fdot2(h2c<2>(hv), h2c<2>(wv), acc, false); \
    acc = __builtin_amdgcn_fdot2(h2c<3>(hv), h2c<3>(wv), acc, false); } while (0)

// Pack weights to fp16, chunked for per-lane 16B loads:
//   WPr[(j2*1024 + col)*8 + j] = W_rec[col][j2*8+j],  j2 = 0..31, col = 0..1023
//   WPi[(i2*1024 + col)*8 + j] = W_in [col][i2*8+j],  i2 = 0..4
__global__ void pack_w(const float* __restrict__ Wr, const float* __restrict__ Wi,
                       _Float16* __restrict__ WPr, _Float16* __restrict__ WPi) {
    const int me = threadIdx.x;           // 0..1023 (= out col)
    const int c  = blockIdx.x;            // 0..36
    if (c < NJ2) {
#pragma unroll
        for (int j = 0; j < 8; j++)
            WPr[((size_t)c * 1024 + me) * 8 + j] = (_Float16)Wr[(size_t)me * Hn + c * 8 + j];
    } else {
        const int i2 = c - NJ2;
#pragma unroll
        for (int j = 0; j < 8; j++)
            WPi[((size_t)i2 * 1024 + me) * 8 + j] = (_Float16)Wi[(size_t)me * In + i2 * 8 + j];
    }
}

// 256 blocks x 512 threads (8 waves, 1 block/CU, waves/EU pinned to 2 so the
// allocator may use 256 VGPRs). Thread (hp = wave*32 + (lane&31), half =
// lane>>5) owns 4 cols hp+256m (one per compartment m) for 2 batch rows
// r0=2*half, r1=r0+1. Lanes l and l+32 read identical weight addresses
// (wave-coalesced); h reads are 2-address broadcasts (free). h_new is fully
// thread-local (softmax over own 4 compartments). W_in + 4 rec chunks live
// in pinned VGPRs; rec chunks 4..31 stream from L2 double-buffered.
__global__ __launch_bounds__(512)
__attribute__((amdgpu_waves_per_eu(2, 2)))
void diru_reg(
    const float* __restrict__ x,
    const _Float16* __restrict__ WPr,
    const _Float16* __restrict__ WPi,
    const float* __restrict__ b_in, const float* __restrict__ b_rec,
    const float* __restrict__ W_gate, const float* __restrict__ b_gate,
    const float* __restrict__ W_fc, const float* __restrict__ b_fc,
    float* __restrict__ out)
{
    const int tid  = threadIdx.x;
    const int lane = tid & 63, wave = tid >> 6;
    const int il   = lane & 31, half = lane >> 5;
    const int hp   = wave * 32 + il;        // 0..255
    const int r0   = half * 2, r1 = r0 + 1; // local rows
    const int b0   = blockIdx.x * 4;

    __shared__ _Float16 hh[4 * Hn];         // h_t fp16, row-major [4][256]
    __shared__ _Float16 xs[4][In];          // x_t fp16
    __shared__ float    red[8][2][8];       // [wave][half][r2*4+kg]

    const half8* __restrict__ WR8 = (const half8*)WPr;
    const half8* __restrict__ WI8 = (const half8*)WPi;

    // col indices (half8 units): chunk c, col m -> c*1024 + hp + 256m
    const int c0 = hp, c1 = hp + 256, c2 = hp + 512, c3 = hp + 768;

    // ---- resident weights, pinned ----
    half8 wik[5][4];
#pragma unroll
    for (int i2 = 0; i2 < 5; i2++) {
        wik[i2][0] = WI8[i2 * 1024 + c0]; wik[i2][1] = WI8[i2 * 1024 + c1];
        wik[i2][2] = WI8[i2 * 1024 + c2]; wik[i2][3] = WI8[i2 * 1024 + c3];
#pragma unroll
        for (int m = 0; m < 4; m++) PIN(wik[i2][m]);
    }
    half8 wrk[RRES][4];
#pragma unroll
    for (int j2 = 0; j2 < RRES; j2++) {
        wrk[j2][0] = WR8[j2 * 1024 + c0]; wrk[j2][1] = WR8[j2 * 1024 + c1];
        wrk[j2][2] = WR8[j2 * 1024 + c2]; wrk[j2][3] = WR8[j2 * 1024 + c3];
#pragma unroll
        for (int m = 0; m < 4; m++) PIN(wrk[j2][m]);
    }
    float Wg[4][4];          // [kg][m]
#pragma unroll
    for (int kg = 0; kg < 4; kg++)
#pragma unroll
        for (int m = 0; m < 4; m++)
            Wg[kg][m] = W_gate[kg * 1024 + hp + 256 * m];
    float bias[4], bg[4];
#pragma unroll
    for (int m = 0; m < 4; m++) bias[m] = b_in[hp + 256 * m] + b_rec[hp + 256 * m];
#pragma unroll
    for (int kg = 0; kg < 4; kg++) bg[kg] = b_gate[kg];

    // ---- init LDS ----
    for (int i = tid; i < 4 * Hn; i += 512) hh[i] = (_Float16)0.f;
    const int  xv_id = tid - 256;                 // threads 256..415 stage x
    const bool is_x  = (xv_id >= 0) && (xv_id < 4 * In);
    const int  xr    = is_x ? (xv_id / In) : 0;
    const int  xi    = is_x ? (xv_id - xr * In) : 0;
    const float* xp  = x + ((size_t)(b0 + xr) * Tn) * In + xi;
    if (is_x) xs[xr][xi] = (_Float16)xp[0];

    half8 sA0, sA1, sA2, sA3, sB0, sB1, sB2, sB3;
#define ISSUE_A(c) { sA0 = WR8[(c) * 1024 + c0]; sA1 = WR8[(c) * 1024 + c1]; \
                     sA2 = WR8[(c) * 1024 + c2]; sA3 = WR8[(c) * 1024 + c3]; }
#define ISSUE_B(c) { sB0 = WR8[(c) * 1024 + c0]; sB1 = WR8[(c) * 1024 + c1]; \
                     sB2 = WR8[(c) * 1024 + c2]; sB3 = WR8[(c) * 1024 + c3]; }
// consume rec chunk c with weights W0..W3 (4 cols), both rows
#define CONS(c, W0, W1, W2, W3) { \
    const half8 hv0 = ld8(&hh[r0 * Hn + (c) * 8]); \
    const half8 hv1 = ld8(&hh[r1 * Hn + (c) * 8]); \
    D8(a00, hv0, W0); D8(a01, hv1, W0); \
    D8(a10, hv0, W1); D8(a11, hv1, W1); \
    D8(a20, hv0, W2); D8(a21, hv1, W2); \
    D8(a30, hv0, W3); D8(a31, hv1, W3); }

    for (int t = 0; t < Tn; t++) {
        // issue next-x + first two streamed chunks before the barrier
        float xpre = 0.f;
        if (is_x && (t + 1 < Tn)) xpre = xp[(size_t)(t + 1) * In];
        ISSUE_A(RRES);          // chunk 4
        ISSUE_B(RRES + 1);      // chunk 5

        __syncthreads();   // hh(t), xs(t) ready

        float a00 = bias[0], a01 = bias[0], a10 = bias[1], a11 = bias[1];
        float a20 = bias[2], a21 = bias[2], a30 = bias[3], a31 = bias[3];

        // ---- input projection (resident) ----
#pragma unroll
        for (int i2 = 0; i2 < 5; i2++) {
            const half8 xv0 = ld8(&xs[r0][i2 * 8]);
            const half8 xv1 = ld8(&xs[r1][i2 * 8]);
            D8(a00, xv0, wik[i2][0]); D8(a01, xv1, wik[i2][0]);
            D8(a10, xv0, wik[i2][1]); D8(a11, xv1, wik[i2][1]);
            D8(a20, xv0, wik[i2][2]); D8(a21, xv1, wik[i2][2]);
            D8(a30, xv0, wik[i2][3]); D8(a31, xv1, wik[i2][3]);
        }
        // ---- recurrent, resident chunks ----
#pragma unroll
        for (int j2 = 0; j2 < RRES; j2++)
            CONS(j2, wrk[j2][0], wrk[j2][1], wrk[j2][2], wrk[j2][3]);

        // ---- recurrent, streamed chunks 4..31, 2-deep double buffer ----
#pragma unroll
        for (int cc = 0; cc < 14; cc++) {
            const int c = RRES + 2 * cc;
            CONS(c, sA0, sA1, sA2, sA3);
            if (c + 2 <= NJ2 - 1) ISSUE_A(c + 2);
            CONS(c + 1, sB0, sB1, sB2, sB3);
            if (c + 3 <= NJ2 - 1) ISSUE_B(c + 3);
        }

        // ---- tanh ----
        const float o00 = tanh_fast(a00), o01 = tanh_fast(a01);
        const float o10 = tanh_fast(a10), o11 = tanh_fast(a11);
        const float o20 = tanh_fast(a20), o21 = tanh_fast(a21);
        const float o30 = tanh_fast(a30), o31 = tanh_fast(a31);

        // ---- gate partials over own 4 cols, butterfly over 32-lane half ----
        float part[2][4];
#pragma unroll
        for (int kg = 0; kg < 4; kg++) {
            part[0][kg] = fmaf(o00, Wg[kg][0], fmaf(o10, Wg[kg][1],
                          fmaf(o20, Wg[kg][2], o30 * Wg[kg][3])));
            part[1][kg] = fmaf(o01, Wg[kg][0], fmaf(o11, Wg[kg][1],
                          fmaf(o21, Wg[kg][2], o31 * Wg[kg][3])));
        }
#pragma unroll
        for (int m = 16; m > 0; m >>= 1) {
#pragma unroll
            for (int r = 0; r < 2; r++)
#pragma unroll
                for (int kg = 0; kg < 4; kg++)
                    part[r][kg] += __shfl_xor(part[r][kg], m, 64);
        }
        if (il == 0) {
#pragma unroll
            for (int r = 0; r < 2; r++)
#pragma unroll
                for (int kg = 0; kg < 4; kg++)
                    red[wave][half][r * 4 + kg] = part[r][kg];
        }
        __syncthreads();   // red ready; all hh reads done

        // ---- softmax (per thread, 2 rows) + thread-local h_new ----
#pragma unroll
        for (int r = 0; r < 2; r++) {
            float l0 = bg[0], l1 = bg[1], l2 = bg[2], l3 = bg[3];
#pragma unroll
            for (int w8 = 0; w8 < 8; w8++) {
                const float4 v = *(const float4*)&red[w8][half][r * 4];
                l0 += v.x; l1 += v.y; l2 += v.z; l3 += v.w;
            }
            const float mx = fmaxf(fmaxf(l0, l1), fmaxf(l2, l3));
            const float e0 = __expf(l0 - mx), e1 = __expf(l1 - mx);
            const float e2 = __expf(l2 - mx), e3 = __expf(l3 - mx);
            const float inv = __builtin_amdgcn_rcpf(e0 + e1 + e2 + e3);
            const float hn = (r == 0)
                ? (e0 * o00 + e1 * o10 + e2 * o20 + e3 * o30) * inv
                : (e0 * o01 + e1 * o11 + e2 * o21 + e3 * o31) * inv;
            hh[(r0 + r) * Hn + hp] = (_Float16)hn;
        }
        if (is_x && (t + 1 < Tn)) xs[xr][xi] = (_Float16)xpre;
        // loop-top barrier orders hh/xs writes vs next step's reads
    }

    __syncthreads();
    // ---- final FC ----
    if (tid < 4 * On) {
        const int r = tid >> 4, o = tid & 15;
        float s = b_fc[o];
#pragma unroll 4
        for (int j8 = 0; j8 < 32; j8++) {
            const half8 hv = ld8(&hh[r * Hn + j8 * 8]);
#pragma unroll
            for (int jj = 0; jj < 8; jj++)
                s = fmaf((float)hv[jj], W_fc[o * Hn + j8 * 8 + jj], s);
        }
        out[(size_t)(b0 + r) * On + o] = s;
    }
#undef ISSUE_A
#undef ISSUE_B
#undef CONS
}

extern "C" void kernel_launch(void* const* d_in, const int* in_sizes, int n_in,
                              void* d_out, int out_size, void* d_ws, size_t ws_size,
                              hipStream_t stream) {
    const float* x      = (const float*)d_in[0];
    const float* W_in   = (const float*)d_in[1];
    const float* b_in   = (const float*)d_in[2];
    const float* W_rec  = (const float*)d_in[3];
    const float* b_rec  = (const float*)d_in[4];
    const float* W_gate = (const float*)d_in[5];
    const float* b_gate = (const float*)d_in[6];
    const float* W_fc   = (const float*)d_in[7];
    const float* b_fc   = (const float*)d_in[8];
    float* out = (float*)d_out;

    _Float16* WPr = (_Float16*)d_ws;          // 32*1024*8 fp16 = 512 KB
    _Float16* WPi = WPr + 262144;             //  5*1024*8 fp16 =  80 KB

    pack_w<<<37, 1024, 0, stream>>>(W_rec, W_in, WPr, WPi);
    diru_reg<<<256, 512, 0, stream>>>(x, WPr, WPi, b_in, b_rec,
                                      W_gate, b_gate, W_fc, b_fc, out);
}